// Round 2
// baseline (79.679 us; speedup 1.0000x reference)
//
#include <hip/hip_runtime.h>
#include <stdint.h>

// One thread per (batch, row). Input mask is binary float32 (0.0f / 1.0f),
// treated as uint32 bit patterns (nonzero == candidate).
//
// Row logic (naked-pair elimination, derived from the reference):
//   cand[w]  = 9-bit candidate mask of cell w
//   for each pair-mask pm with popcount 2 occurring EXACTLY twice in the row:
//     cells with cand != pm get pm's digits erased
//   out(d,w) = (cand[w] & ~clear[w])>>d  as 1.0f/0.0f bit patterns.
//
// R2 changes vs R1: load ALL 81 words into registers up front (27 wide loads
// in flight -> hide HBM/L3 latency with ILP, not just TLP), non-temporal
// stores (don't evict the L3-resident input with write traffic).

typedef uint32_t u32x4 __attribute__((ext_vector_type(4)));
typedef u32x4 u32x4_u __attribute__((aligned(4)));

__global__ __launch_bounds__(256) void sudoku_rows_kernel(
    const uint32_t* __restrict__ in, uint32_t* __restrict__ out, int nrows) {
  int gid = blockIdx.x * blockDim.x + threadIdx.x;
  if (gid >= nrows) return;
  int b = gid / 9;
  int h = gid - b * 9;
  const uint32_t* base = in + (size_t)b * 729 + h * 9;  // + d*81 + w

  // Issue all 27 loads (9 planes x {x4,x4,x1}) before any dependent use.
  uint32_t t[9][9];
#pragma unroll
  for (int d = 0; d < 9; ++d)
    __builtin_memcpy(&t[d][0], base + d * 81, 36);  // 9 contiguous words

  // Per-cell candidate bitmasks.
  uint32_t cand[9];
#pragma unroll
  for (int w = 0; w < 9; ++w) {
    uint32_t c = 0;
#pragma unroll
    for (int d = 0; d < 9; ++d) c |= (t[d][w] ? 1u : 0u) << d;
    cand[w] = c;
  }

  // Pair-values occurring exactly twice -> per-cell clear masks.
  uint32_t clearbits[9];
#pragma unroll
  for (int w = 0; w < 9; ++w) clearbits[w] = 0u;
#pragma unroll
  for (int w1 = 0; w1 < 9; ++w1) {
    uint32_t c1 = cand[w1];
    if (__popc(c1) != 2) continue;
    int cnt = 0;
#pragma unroll
    for (int w2 = 0; w2 < 9; ++w2) cnt += (cand[w2] == c1) ? 1 : 0;
    if (cnt == 2) {
#pragma unroll
      for (int w = 0; w < 9; ++w)
        if (cand[w] != c1) clearbits[w] |= c1;
    }
  }

  uint32_t keep[9];
#pragma unroll
  for (int w = 0; w < 9; ++w) keep[w] = cand[w] & ~clearbits[w];

  // Non-temporal stores: 2x dwordx4 + 1x dword per d-plane.
  uint32_t* obase = out + (size_t)b * 729 + h * 9;
#pragma unroll
  for (int d = 0; d < 9; ++d) {
    uint32_t v[9];
#pragma unroll
    for (int w = 0; w < 9; ++w)
      v[w] = ((keep[w] >> d) & 1u) ? 0x3F800000u : 0u;
    u32x4_u* p0 = (u32x4_u*)(obase + d * 81);
    u32x4_u* p1 = (u32x4_u*)(obase + d * 81 + 4);
    u32x4 v0 = {v[0], v[1], v[2], v[3]};
    u32x4 v1 = {v[4], v[5], v[6], v[7]};
    __builtin_nontemporal_store(v0, p0);
    __builtin_nontemporal_store(v1, p1);
    __builtin_nontemporal_store(v[8], obase + d * 81 + 8);
  }
}

extern "C" void kernel_launch(void* const* d_in, const int* in_sizes, int n_in,
                              void* d_out, int out_size, void* d_ws, size_t ws_size,
                              hipStream_t stream) {
  const uint32_t* in = (const uint32_t*)d_in[0];  // mask, float32 binary
  uint32_t* out = (uint32_t*)d_out;               // float32 out, bit-patterns
  int B = in_sizes[0] / 729;
  int nrows = B * 9;
  const int threads = 256;
  int blocks = (nrows + threads - 1) / threads;
  sudoku_rows_kernel<<<blocks, threads, 0, stream>>>(in, out, nrows);
}

// Round 3
// 45.741 us; speedup vs baseline: 1.7420x; 1.7420x over previous
//
#include <hip/hip_runtime.h>
#include <stdint.h>

// 2 threads per (batch, row), paired by lane parity. Input mask is binary
// float32 (exactly 0.0f / 1.0f) treated as uint32 bit patterns.
//
// Row logic (naked-pair elimination, derived from the reference):
//   cand[w]  = 9-bit candidate mask of cell w
//   for each pair-mask pm with popcount 2 occurring EXACTLY twice in the row:
//     cells with cand != pm get pm's digits erased
//   out(d,w) = (cand[w] & ~clear[w])>>d as 1.0f/0.0f bit patterns.
//
// R3: split the 9 d-planes across a lane pair (half0: d=0..4, half1: d=4..8,
// plane 4 duplicated for a uniform 5-iteration loop), merge candidate masks
// with one shfl_xor, redundantly compute the pair logic (VALU is ~5% busy),
// write disjoint planes (half0: 0-3, half1: 4-8). Doubles wave count
// 18 -> 36 per CU to attack the latency-bound regime. Regular stores (R2's
// non-temporal stores inflated WRITE_SIZE 95->177 MB via partial-line
// eviction).

__global__ __launch_bounds__(256) void sudoku_rows_kernel(
    const uint32_t* __restrict__ in, uint32_t* __restrict__ out, int nthreads) {
  int gid = blockIdx.x * blockDim.x + threadIdx.x;
  if (gid >= nthreads) return;
  int row = gid >> 1;
  int half = gid & 1;
  int b = row / 9;
  int h = row - b * 9;
  const uint32_t* base = in + (size_t)b * 729 + h * 9;  // + d*81 + w
  int d0 = half * 4;

  // Load my 5 planes (lane-uniform loop; plane 4 read by both halves).
  uint32_t t[5][9];
#pragma unroll
  for (int k = 0; k < 5; ++k)
    __builtin_memcpy(&t[k][0], base + (d0 + k) * 81, 36);

  // Partial candidate masks from my planes (plane-4 overlap is idempotent).
  uint32_t part[9];
#pragma unroll
  for (int w = 0; w < 9; ++w) {
    uint32_t c = 0;
#pragma unroll
    for (int k = 0; k < 5; ++k) c |= (t[k][w] ? 1u : 0u) << (d0 + k);
    part[w] = c;
  }

  // Merge with partner lane -> full 9-bit cand per cell.
  uint32_t cand[9];
#pragma unroll
  for (int w = 0; w < 9; ++w) cand[w] = part[w] | __shfl_xor(part[w], 1);

  // Pair-values occurring exactly twice -> per-cell clear masks.
  uint32_t clearbits[9];
#pragma unroll
  for (int w = 0; w < 9; ++w) clearbits[w] = 0u;
#pragma unroll
  for (int w1 = 0; w1 < 9; ++w1) {
    uint32_t c1 = cand[w1];
    if (__popc(c1) != 2) continue;
    int cnt = 0;
#pragma unroll
    for (int w2 = 0; w2 < 9; ++w2) cnt += (cand[w2] == c1) ? 1 : 0;
    if (cnt == 2) {
#pragma unroll
      for (int w = 0; w < 9; ++w)
        if (cand[w] != c1) clearbits[w] |= c1;
    }
  }

  uint32_t keep[9];
#pragma unroll
  for (int w = 0; w < 9; ++w) keep[w] = cand[w] & ~clearbits[w];

  // Write my planes: half0 -> d=0..3, half1 -> d=4..8.
  uint32_t* obase = out + (size_t)b * 729 + h * 9;
#pragma unroll
  for (int k = 0; k < 4; ++k) {
    int d = d0 + k;
    uint32_t v[9];
#pragma unroll
    for (int w = 0; w < 9; ++w)
      v[w] = ((keep[w] >> d) & 1u) ? 0x3F800000u : 0u;
    __builtin_memcpy(obase + d * 81, v, 36);
  }
  if (half) {
    uint32_t v[9];
#pragma unroll
    for (int w = 0; w < 9; ++w)
      v[w] = ((keep[w] >> 8) & 1u) ? 0x3F800000u : 0u;
    __builtin_memcpy(obase + 8 * 81, v, 36);
  }
}

extern "C" void kernel_launch(void* const* d_in, const int* in_sizes, int n_in,
                              void* d_out, int out_size, void* d_ws, size_t ws_size,
                              hipStream_t stream) {
  const uint32_t* in = (const uint32_t*)d_in[0];  // mask, float32 binary
  uint32_t* out = (uint32_t*)d_out;               // float32 out, bit-patterns
  int B = in_sizes[0] / 729;
  int nthreads = B * 9 * 2;
  const int threads = 256;
  int blocks = (nthreads + threads - 1) / threads;
  sudoku_rows_kernel<<<blocks, threads, 0, stream>>>(in, out, nthreads);
}

// Round 4
// 44.277 us; speedup vs baseline: 1.7996x; 1.0331x over previous
//
#include <hip/hip_runtime.h>
#include <stdint.h>

// 2 threads per (batch, row), paired by lane parity. Input mask is binary
// float32 (exactly 0.0f / 1.0f) treated as uint32 bit patterns.
//
// Row logic (naked-pair elimination, derived from the reference):
//   cand[w]  = 9-bit candidate mask of cell w
//   for each pair-mask pm with popcount 2 occurring EXACTLY twice in the row:
//     cells with cand != pm get pm's digits erased
//   out(d,w) = (cand[w] & ~clear[w])>>d as 1.0f/0.0f bit patterns.
//
// R4: R3 was latency-bound with VGPR_Count=28 -- the compiler serialized the
// 5 plane loads into load->use->load->use round-trips. Here the load phase is
// pinned BEFORE the compute phase with sched_barrier(0): all 15 VMEM ops
// issue back-to-back (45 words live in registers), overlapping their latency.

typedef uint32_t u32x4 __attribute__((ext_vector_type(4), aligned(4)));

__global__ __launch_bounds__(256) void sudoku_rows_kernel(
    const uint32_t* __restrict__ in, uint32_t* __restrict__ out, int nthreads) {
  int gid = blockIdx.x * blockDim.x + threadIdx.x;
  if (gid >= nthreads) return;
  int row = gid >> 1;
  int half = gid & 1;
  int b = row / 9;
  int h = row - b * 9;
  const uint32_t* base = in + (size_t)b * 729 + h * 9;  // + d*81 + w
  int d0 = half * 4;

  // ---- Phase 1: issue ALL loads (5 planes x 36 B = 15 VMEM) ----
  u32x4 vlo[5], vhi[5];
  uint32_t vlast[5];
#pragma unroll
  for (int k = 0; k < 5; ++k) {
    const uint32_t* p = base + (d0 + k) * 81;
    vlo[k] = *(const u32x4*)p;        // 4B-aligned dwordx4 ok on gfx950
    vhi[k] = *(const u32x4*)(p + 4);
    vlast[k] = p[8];
  }
  // Pin: nothing moves across -- loads stay hoisted, all 45 values live.
  __builtin_amdgcn_sched_barrier(0);

  // ---- Phase 2: fold into partial candidate masks ----
  uint32_t part[9];
#pragma unroll
  for (int w = 0; w < 9; ++w) part[w] = 0u;
#pragma unroll
  for (int k = 0; k < 5; ++k) {
    uint32_t tw[9] = {vlo[k][0], vlo[k][1], vlo[k][2], vlo[k][3],
                      vhi[k][0], vhi[k][1], vhi[k][2], vhi[k][3], vlast[k]};
#pragma unroll
    for (int w = 0; w < 9; ++w) part[w] |= (tw[w] ? 1u : 0u) << (d0 + k);
  }

  // Merge with partner lane -> full 9-bit cand per cell (plane-4 overlap
  // between the halves is idempotent under OR).
  uint32_t cand[9];
#pragma unroll
  for (int w = 0; w < 9; ++w) cand[w] = part[w] | __shfl_xor(part[w], 1);

  // Pair-values occurring exactly twice -> per-cell clear masks.
  uint32_t clearbits[9];
#pragma unroll
  for (int w = 0; w < 9; ++w) clearbits[w] = 0u;
#pragma unroll
  for (int w1 = 0; w1 < 9; ++w1) {
    uint32_t c1 = cand[w1];
    if (__popc(c1) != 2) continue;
    int cnt = 0;
#pragma unroll
    for (int w2 = 0; w2 < 9; ++w2) cnt += (cand[w2] == c1) ? 1 : 0;
    if (cnt == 2) {
#pragma unroll
      for (int w = 0; w < 9; ++w)
        if (cand[w] != c1) clearbits[w] |= c1;
    }
  }

  uint32_t keep[9];
#pragma unroll
  for (int w = 0; w < 9; ++w) keep[w] = cand[w] & ~clearbits[w];

  // ---- Phase 3: write my planes (half0: d=0..3, half1: d=4..8) ----
  uint32_t* obase = out + (size_t)b * 729 + h * 9;
#pragma unroll
  for (int k = 0; k < 4; ++k) {
    int d = d0 + k;
    uint32_t v[9];
#pragma unroll
    for (int w = 0; w < 9; ++w)
      v[w] = ((keep[w] >> d) & 1u) ? 0x3F800000u : 0u;
    __builtin_memcpy(obase + d * 81, v, 36);
  }
  if (half) {
    uint32_t v[9];
#pragma unroll
    for (int w = 0; w < 9; ++w)
      v[w] = ((keep[w] >> 8) & 1u) ? 0x3F800000u : 0u;
    __builtin_memcpy(obase + 8 * 81, v, 36);
  }
}

extern "C" void kernel_launch(void* const* d_in, const int* in_sizes, int n_in,
                              void* d_out, int out_size, void* d_ws, size_t ws_size,
                              hipStream_t stream) {
  const uint32_t* in = (const uint32_t*)d_in[0];  // mask, float32 binary
  uint32_t* out = (uint32_t*)d_out;               // float32 out, bit-patterns
  int B = in_sizes[0] / 729;
  int nthreads = B * 9 * 2;
  const int threads = 256;
  int blocks = (nthreads + threads - 1) / threads;
  sudoku_rows_kernel<<<blocks, threads, 0, stream>>>(in, out, nthreads);
}

// Round 5
// 35.034 us; speedup vs baseline: 2.2743x; 1.2638x over previous
//
#include <hip/hip_runtime.h>
#include <stdint.h>

// R5: LDS-staged, memcpy-shaped memory phases.
//   Phase 1: 8 batches (5832 words, 22.8 KB) global->LDS via global_load_lds
//            16B DMA chunks, fully coalesced, no VGPR round-trip.
//   Phase 2: 72 threads = one per (batch,row): build 9-bit candidate masks
//            from LDS, naked-pair elimination, write 1.0f/0.0f patterns back
//            to the same (thread-private) LDS words.
//   Phase 3: coalesced dwordx4 LDS->global stores (full-line coverage).
//
// Row logic (validated R1-R4, absmax 0): cand[w] = candidate bitmask of cell
// w; every pair-mask (popcount 2) occurring exactly twice in the row erases
// its digits from all cells whose cand differs from it.

#define GBATCH 8
#define WORDS_PER_WG (GBATCH * 729)  // 5832 words = 23328 B
#define CHUNKS (WORDS_PER_WG / 4)    // 1458 16B chunks

typedef uint32_t u32x4 __attribute__((ext_vector_type(4)));
typedef const __attribute__((address_space(1))) uint32_t* gsrc_t;
typedef __attribute__((address_space(3))) uint32_t* lptr_t;

__global__ __launch_bounds__(256) void sudoku_kernel(
    const uint32_t* __restrict__ in, uint32_t* __restrict__ out) {
  __shared__ uint32_t lds[WORDS_PER_WG];
  const int g = blockIdx.x;
  const int t = threadIdx.x;
  const uint32_t* gin = in + (size_t)g * WORDS_PER_WG;

  // ---- Phase 1: global -> LDS, 16B DMA, coalesced ----
#pragma unroll
  for (int j = 0; j < 6; ++j) {
    int i = t + j * 256;
    if (i < CHUNKS) {
      __builtin_amdgcn_global_load_lds((gsrc_t)(gin + i * 4),
                                       (lptr_t)(&lds[i * 4]), 16, 0, 0);
    }
  }
  __syncthreads();  // drains vmcnt (LDS-DMA) before any LDS read

  // ---- Phase 2: per-row naked-pair logic ----
  if (t < GBATCH * 9) {
    const int bl = t / 9;
    const int h = t - bl * 9;
    const int rbase = bl * 729 + h * 9;

    uint32_t cand[9];
#pragma unroll
    for (int w = 0; w < 9; ++w) cand[w] = 0u;
#pragma unroll
    for (int d = 0; d < 9; ++d) {
#pragma unroll
      for (int w = 0; w < 9; ++w)
        cand[w] |= (lds[rbase + d * 81 + w] ? 1u : 0u) << d;
    }

    uint32_t clearbits[9];
#pragma unroll
    for (int w = 0; w < 9; ++w) clearbits[w] = 0u;
#pragma unroll
    for (int w1 = 0; w1 < 9; ++w1) {
      uint32_t c1 = cand[w1];
      if (__popc(c1) != 2) continue;
      int cnt = 0;
#pragma unroll
      for (int w2 = 0; w2 < 9; ++w2) cnt += (cand[w2] == c1) ? 1 : 0;
      if (cnt == 2) {
#pragma unroll
        for (int w = 0; w < 9; ++w)
          if (cand[w] != c1) clearbits[w] |= c1;
      }
    }

    uint32_t keep[9];
#pragma unroll
    for (int w = 0; w < 9; ++w) keep[w] = cand[w] & ~clearbits[w];

    // Write 1.0f/0.0f patterns back to the same (thread-private) words.
#pragma unroll
    for (int d = 0; d < 9; ++d) {
#pragma unroll
      for (int w = 0; w < 9; ++w)
        lds[rbase + d * 81 + w] =
            ((keep[w] >> d) & 1u) ? 0x3F800000u : 0u;
    }
  }
  __syncthreads();

  // ---- Phase 3: LDS -> global, dwordx4, coalesced ----
  uint32_t* gout = out + (size_t)g * WORDS_PER_WG;
#pragma unroll
  for (int j = 0; j < 6; ++j) {
    int i = t + j * 256;
    if (i < CHUNKS) {
      u32x4 v = {lds[i * 4], lds[i * 4 + 1], lds[i * 4 + 2], lds[i * 4 + 3]};
      *(u32x4*)(gout + i * 4) = v;  // 16B aligned (g*23328 + i*16)
    }
  }
}

extern "C" void kernel_launch(void* const* d_in, const int* in_sizes, int n_in,
                              void* d_out, int out_size, void* d_ws, size_t ws_size,
                              hipStream_t stream) {
  const uint32_t* in = (const uint32_t*)d_in[0];  // mask, float32 binary
  uint32_t* out = (uint32_t*)d_out;               // float32 out, bit-patterns
  int B = in_sizes[0] / 729;
  int blocks = B / GBATCH;  // B = 32768 -> 4096 WGs
  sudoku_kernel<<<blocks, 256, 0, stream>>>(in, out);
}